// Round 1
// baseline (202.626 us; speedup 1.0000x reference)
//
#include <hip/hip_runtime.h>
#include <hip/hip_bf16.h>

// ChannelDense: y[b,n,o] = tanh( sum_i x[b,n,i] * W[c[n],o,i] + bias[c[n],o] ) + x[b,n,o]
// B=128, N=2048, IN=OUT=256, NUM_CHANNELS=64.
// One workgroup per n: GEMM M=128 (batch) x N=256 (out) x K=256 (in), bf16 MFMA, f32 accum.
// LDS: A = x-tile [128][256] bf16 (64KB, swizzled, also residual source)
//      B = W-slice [256][32] bf16 (16KB, swizzled)  -> 80KB total => 2 wg/CU.

#define B_SZ  128
#define N_SZ  2048
#define IN_F  256
#define OUT_F 256

typedef __attribute__((ext_vector_type(8))) __bf16 bf16x8;
typedef __attribute__((ext_vector_type(4))) float  f32x4;

__device__ __forceinline__ unsigned f2bf1(float f) {
    union { float f; unsigned u; } v; v.f = f;
    return (v.u + 0x7fffu + ((v.u >> 16) & 1u)) >> 16;   // RNE
}
__device__ __forceinline__ int pack2(float lo, float hi) {
    return (int)(f2bf1(lo) | (f2bf1(hi) << 16));
}
__device__ __forceinline__ float bf2f(unsigned short u) {
    union { unsigned u; float f; } v; v.u = ((unsigned)u) << 16;
    return v.f;
}
__device__ __forceinline__ float tanh_fast(float s) {
    float a = fabsf(s);
    float t = __expf(-2.0f * a);                          // in (0,1], no overflow
    float r = (1.0f - t) * __builtin_amdgcn_rcpf(1.0f + t);
    return s < 0.0f ? -r : r;
}

__global__ __launch_bounds__(512, 4) void channel_dense_kernel(
    const float* __restrict__ x, const int* __restrict__ channels,
    const float* __restrict__ weight, const float* __restrict__ bias,
    float* __restrict__ y)
{
    __shared__ __align__(16) unsigned char smem[65536 + 16384];
    unsigned char* sA = smem;             // [128][256] bf16, row stride 512B, byte ^= (row&15)<<4
    unsigned char* sB = smem + 65536;     // [256][32]  bf16, row stride  64B, byte ^= (o&3)<<4

    const int n   = blockIdx.x;
    const int tid = threadIdx.x;
    const int c   = channels[n];
    const float* wch = weight + (size_t)c * (OUT_F * IN_F);

    // ---- stage A once: x[:, n, :] -> bf16 LDS ----
    {
        const int row = tid >> 2;          // 0..127 (batch b)
        const int sub = tid & 3;           // 0..3, 64 floats each
        const float* xrow = x + ((size_t)row * N_SZ + n) * IN_F + sub * 64;
        const int swz = (row & 15) << 4;
        #pragma unroll
        for (int j = 0; j < 8; ++j) {
            float4 f0 = *(const float4*)(xrow + j * 8);
            float4 f1 = *(const float4*)(xrow + j * 8 + 4);
            int4 p;
            p.x = pack2(f0.x, f0.y); p.y = pack2(f0.z, f0.w);
            p.z = pack2(f1.x, f1.y); p.w = pack2(f1.z, f1.w);
            int byte = (row * 512 + (sub * 64 + j * 8) * 2) ^ swz;
            *(int4*)(sA + byte) = p;
        }
    }

    // ---- B staging helper: W[c][o][kt*32 .. +32] -> bf16 LDS ----
    const int bo = tid >> 1;               // 0..255 (out row)
    const int bh = tid & 1;                // half of 32-k slice
    const int bswz = (bo & 3) << 4;
    auto stageB = [&](int kt) {
        const float* wrow = wch + (size_t)bo * IN_F + kt * 32 + bh * 16;
        float4 f0 = *(const float4*)(wrow);
        float4 f1 = *(const float4*)(wrow + 4);
        float4 f2 = *(const float4*)(wrow + 8);
        float4 f3 = *(const float4*)(wrow + 12);
        int4 p0, p1;
        p0.x = pack2(f0.x, f0.y); p0.y = pack2(f0.z, f0.w);
        p0.z = pack2(f1.x, f1.y); p0.w = pack2(f1.z, f1.w);
        p1.x = pack2(f2.x, f2.y); p1.y = pack2(f2.z, f2.w);
        p1.z = pack2(f3.x, f3.y); p1.w = pack2(f3.z, f3.w);
        int base = bo * 64 + bh * 32;
        *(int4*)(sB + ((base)      ^ bswz)) = p0;
        *(int4*)(sB + ((base + 16) ^ bswz)) = p1;
    };
    stageB(0);
    __syncthreads();

    // ---- MFMA main loop ----
    const int wv   = tid >> 6;             // 0..7
    const int lane = tid & 63;
    const int wr   = wv >> 2;              // 0..1  (row 64-block)
    const int wc   = wv & 3;               // 0..3  (col 64-block)
    const int lr   = lane & 15;
    const int lkb  = (lane >> 4) * 16;     // byte offset of this lane's 8 bf16 in k

    f32x4 acc[4][4] = {};

    for (int kt = 0; kt < 8; ++kt) {
        bf16x8 af[4], bfr[4];
        #pragma unroll
        for (int m = 0; m < 4; ++m) {
            int row  = wr * 64 + m * 16 + lr;
            int byte = (row * 512 + kt * 64 + lkb) ^ ((row & 15) << 4);
            af[m] = *(const bf16x8*)(sA + byte);
        }
        #pragma unroll
        for (int nf = 0; nf < 4; ++nf) {
            int o    = wc * 64 + nf * 16 + lr;
            int byte = (o * 64 + lkb) ^ ((o & 3) << 4);
            bfr[nf] = *(const bf16x8*)(sB + byte);
        }
        #pragma unroll
        for (int m = 0; m < 4; ++m)
            #pragma unroll
            for (int nf = 0; nf < 4; ++nf)
                acc[m][nf] = __builtin_amdgcn_mfma_f32_16x16x32_bf16(af[m], bfr[nf], acc[m][nf], 0, 0, 0);

        if (kt < 7) {
            __syncthreads();               // all reads of sB done
            stageB(kt + 1);
            __syncthreads();               // sB(kt+1) visible
        }
    }

    // ---- epilogue: + bias, tanh, + residual (from bf16 A tile), store ----
    const float* bch = bias + (size_t)c * OUT_F;
    #pragma unroll
    for (int m = 0; m < 4; ++m) {
        #pragma unroll
        for (int r = 0; r < 4; ++r) {
            int brow = wr * 64 + m * 16 + (lane >> 4) * 4 + r;   // C/D row (m89 layout)
            float* yrow = y + ((size_t)brow * N_SZ + n) * OUT_F;
            int aswz = (brow & 15) << 4;
            #pragma unroll
            for (int nf = 0; nf < 4; ++nf) {
                int o = wc * 64 + nf * 16 + lr;                  // C/D col = lane&15
                float s = acc[m][nf][r] + bch[o];
                float t = tanh_fast(s);
                unsigned short us = *(const unsigned short*)(sA + ((brow * 512 + o * 2) ^ aswz));
                yrow[o] = t + bf2f(us);
            }
        }
    }
}

__global__ void channels_copy_kernel(const int* __restrict__ ch, float* __restrict__ out) {
    int i = blockIdx.x * 256 + threadIdx.x;
    if (i < N_SZ) out[i] = (float)ch[i];
}

extern "C" void kernel_launch(void* const* d_in, const int* in_sizes, int n_in,
                              void* d_out, int out_size, void* d_ws, size_t ws_size,
                              hipStream_t stream) {
    const float* x        = (const float*)d_in[0];
    const int*   channels = (const int*)d_in[1];
    const float* weight   = (const float*)d_in[2];
    const float* bias     = (const float*)d_in[3];
    float* y = (float*)d_out;

    channel_dense_kernel<<<dim3(N_SZ), dim3(512), 0, stream>>>(x, channels, weight, bias, y);
    channels_copy_kernel<<<dim3(N_SZ / 256), dim3(256), 0, stream>>>(
        channels, y + (size_t)B_SZ * N_SZ * OUT_F);
}